// Round 12
// baseline (257.993 us; speedup 1.0000x reference)
//
#include <hip/hip_runtime.h>
#include <cmath>

typedef unsigned short u16;
typedef __attribute__((ext_vector_type(8))) short bf16x8;
typedef __attribute__((ext_vector_type(4))) float f32x4;

#define B_    2
#define SEQ_  2048
#define NH_   10
#define HD_   128
#define DIM_  1280

__device__ __forceinline__ u16 f2bf(float f) {
    union { float f; unsigned u; } v; v.f = f;
    unsigned r = (v.u + 0x7fffu + ((v.u >> 16) & 1u)) >> 16;
    return (u16)r;
}
__device__ __forceinline__ float bf2f(u16 h) {
    union { unsigned u; float f; } v; v.u = ((unsigned)h) << 16;
    return v.f;
}
__device__ __forceinline__ f32x4 mfma16(bf16x8 a, bf16x8 b, f32x4 c) {
    return __builtin_amdgcn_mfma_f32_16x16x32_bf16(a, b, c, 0, 0, 0);
}
__device__ __forceinline__ void g2l16(const void* g, void* l) {
    __builtin_amdgcn_global_load_lds(
        (const __attribute__((address_space(1))) unsigned*)g,
        (__attribute__((address_space(3))) unsigned*)l, 16, 0, 0);
}
__device__ __forceinline__ ushort4 pack4(float a, float b, float c, float d) {
    ushort4 w; w.x = f2bf(a); w.y = f2bf(b); w.z = f2bf(c); w.w = f2bf(d);
    return w;
}

// ---- merged convert + sincos: x + 4 weights -> bf16, then ct/st tables ----
__global__ __launch_bounds__(256) void cvt_k(const float* __restrict__ x,
                                             const float* __restrict__ w0,
                                             const float* __restrict__ w1,
                                             const float* __restrict__ w2,
                                             const float* __restrict__ w3,
                                             u16* __restrict__ xb,
                                             u16* __restrict__ d0,
                                             u16* __restrict__ d1,
                                             u16* __restrict__ d2,
                                             u16* __restrict__ d3,
                                             float* __restrict__ ct,
                                             float* __restrict__ st) {
    const int NX = B_ * SEQ_ * DIM_;          // 5,242,880
    const int WN = DIM_ * DIM_;               // 1,638,400
    const int NCV = (NX + 4 * WN) / 8 / 256;  // 5760 convert blocks
    int bid = blockIdx.x;
    if (bid >= NCV) {                          // sincos tail: 512 blocks
        int idx = (bid - NCV) * 256 + threadIdx.x;
        int s = idx >> 6, j = idx & 63;
        float e = (float)j * (1.0f / 64.0f);
        float theta = 1.0f / powf(10000.0f, e);
        float ang = (float)s * theta;
        ct[idx] = cosf(ang);
        st[idx] = sinf(ang);
        return;
    }
    int i = (bid * 256 + threadIdx.x) * 8;
    const float* src; u16* dst; int off;
    if (i < NX) { src = x; dst = xb; off = i; }
    else {
        int j = i - NX; int w = j / WN; off = j - w * WN;
        src = (w == 0) ? w0 : (w == 1) ? w1 : (w == 2) ? w2 : w3;
        dst = (w == 0) ? d0 : (w == 1) ? d1 : (w == 2) ? d2 : d3;
    }
    float4 a0 = *(const float4*)(src + off);
    float4 a1 = *(const float4*)(src + off + 4);
    union { uint4 q; u16 u[8]; } t;
    t.u[0] = f2bf(a0.x); t.u[1] = f2bf(a0.y);
    t.u[2] = f2bf(a0.z); t.u[3] = f2bf(a0.w);
    t.u[4] = f2bf(a1.x); t.u[5] = f2bf(a1.y);
    t.u[6] = f2bf(a1.z); t.u[7] = f2bf(a1.w);
    *(uint4*)(dst + off) = t.q;
}

// ------- GEMM core: 128x128 tile, BK=64, global_load_lds DMA, XOR-swizzled
// 64-wide rows (conflict-free). Proven R11 structure. -------
template <typename OT>
__device__ __forceinline__ void gemm_core(const u16* __restrict__ A,
                                          const u16* __restrict__ W,
                                          const float* __restrict__ bias,
                                          OT* __restrict__ C,
                                          int m_blk, int n_blk,
                                          u16* As, u16* Bs) {
    const int tid = threadIdx.x;
    const int wave = tid >> 6, lane = tid & 63;
    const int quad = lane >> 4, l16 = lane & 15;
    const int w_m = (wave >> 1) * 64, w_n = (wave & 1) * 64;
    const int srow = wave * 32;
    const int lrow = lane >> 3;                       // 0..7
    const int csw = ((lane & 7) ^ lrow) * 8;          // swizzled src chunk
    const int rsw = l16 & 7;                          // reader chunk xor
    f32x4 acc[4][4] = {};

    const u16* pa = A + (size_t)(m_blk + srow + lrow) * DIM_ + csw;
    const u16* pb = W + (size_t)(n_blk + srow + lrow) * DIM_ + csw;

    for (int k0 = 0; k0 < DIM_; k0 += 64) {
        #pragma unroll
        for (int i = 0; i < 4; ++i) {
            g2l16(pa + k0 + i * 8 * DIM_, As + (srow + i * 8) * 64);
            g2l16(pb + k0 + i * 8 * DIM_, Bs + (srow + i * 8) * 64);
        }
        __syncthreads();          // staging visible
        #pragma unroll
        for (int kk = 0; kk < 2; ++kk) {
            bf16x8 af[4], bf[4];
            #pragma unroll
            for (int mt = 0; mt < 4; ++mt)
                af[mt] = *(const bf16x8*)&As[(w_m + mt * 16 + l16) * 64
                                             + ((kk * 4 + quad) ^ rsw) * 8];
            #pragma unroll
            for (int nt = 0; nt < 4; ++nt)
                bf[nt] = *(const bf16x8*)&Bs[(w_n + nt * 16 + l16) * 64
                                             + ((kk * 4 + quad) ^ rsw) * 8];
            #pragma unroll
            for (int mt = 0; mt < 4; ++mt)
                #pragma unroll
                for (int nt = 0; nt < 4; ++nt)
                    acc[mt][nt] = mfma16(af[mt], bf[nt], acc[mt][nt]);
        }
        __syncthreads();          // frag reads done before next staging
    }
    #pragma unroll
    for (int nt = 0; nt < 4; ++nt) {
        int col = n_blk + w_n + nt * 16 + l16;
        float bv = bias[col];
        #pragma unroll
        for (int mt = 0; mt < 4; ++mt) {
            #pragma unroll
            for (int r = 0; r < 4; ++r) {
                int row = m_blk + w_m + mt * 16 + quad * 4 + r;
                float v = acc[mt][nt][r] + bv;
                if constexpr (sizeof(OT) == 4) C[(size_t)row * DIM_ + col] = v;
                else C[(size_t)row * DIM_ + col] = (OT)f2bf(v);
            }
        }
    }
}

__global__ __launch_bounds__(256) void qkv_gemm(const u16* __restrict__ xb,
                                                const u16* __restrict__ Wqb,
                                                const u16* __restrict__ Wkb,
                                                const u16* __restrict__ Wvb,
                                                const float* __restrict__ bq,
                                                const float* __restrict__ bk,
                                                const float* __restrict__ bv,
                                                u16* __restrict__ Qb,
                                                u16* __restrict__ Kb,
                                                u16* __restrict__ Vb) {
    __shared__ alignas(16) u16 As[128 * 64];
    __shared__ alignas(16) u16 Bs[128 * 64];
    int bx = blockIdx.x;
    int wsel = bx / 10, n_blk = (bx % 10) * 128, m_blk = blockIdx.y * 128;
    const u16* W = (wsel == 0) ? Wqb : (wsel == 1) ? Wkb : Wvb;
    const float* bias = (wsel == 0) ? bq : (wsel == 1) ? bk : bv;
    u16* C = (wsel == 0) ? Qb : (wsel == 1) ? Kb : Vb;
    gemm_core<u16>(xb, W, bias, C, m_blk, n_blk, As, Bs);
}

__global__ __launch_bounds__(256) void out_gemm(const u16* __restrict__ AO,
                                                const u16* __restrict__ Wob,
                                                const float* __restrict__ bo,
                                                float* __restrict__ C) {
    __shared__ alignas(16) u16 As[128 * 64];
    __shared__ alignas(16) u16 Bs[128 * 64];
    gemm_core<float>(AO, Wob, bo, C, blockIdx.y * 128, blockIdx.x * 128, As, Bs);
}

// -------- RoPE: Q -> linear Qd (pre-scaled); K -> fragment-packed Kp --------
__global__ __launch_bounds__(256) void rope_k(const u16* __restrict__ Qs_,
                                              const u16* __restrict__ Ks_,
                                              u16* __restrict__ Qd,
                                              u16* __restrict__ Kp,
                                              const float* __restrict__ ct,
                                              const float* __restrict__ st,
                                              float qscale) {
    int t = blockIdx.x * 256 + threadIdx.x;     // 2*NR*8 threads total
    const int NR = B_ * SEQ_ * NH_;
    int rid = t >> 3, j0 = (t & 7) * 8;
    const bool isQ = (rid < NR);
    const u16* src = isQ ? Qs_ : Ks_;
    float sc = isQ ? qscale : 1.0f;
    if (!isQ) rid -= NR;
    int h = rid % NH_;
    int s = (rid / NH_) % SEQ_;
    int b = rid / (NH_ * SEQ_);
    const u16* p = src + (size_t)rid * HD_ + 2 * j0;
    union { uint4 q; u16 u[8]; } a0, a1, o1, o2;
    a0.q = *(const uint4*)p;
    a1.q = *(const uint4*)(p + 8);
    const float* cc = ct + (size_t)s * 64 + j0;
    const float* ss = st + (size_t)s * 64 + j0;
    #pragma unroll
    for (int j = 0; j < 8; ++j) {
        float x1 = bf2f((j < 4) ? a0.u[2 * j] : a1.u[2 * j - 8]);
        float x2 = bf2f((j < 4) ? a0.u[2 * j + 1] : a1.u[2 * j - 7]);
        float c = cc[j], sn = ss[j];
        o1.u[j] = f2bf((x1 * c - x2 * sn) * sc);
        o2.u[j] = f2bf((x1 * sn + x2 * c) * sc);
    }
    if (isQ) {
        u16* q = Qd + (size_t)(((size_t)b * SEQ_ + s) * NH_ + h) * HD_;
        *(uint4*)(q + j0) = o1.q;
        *(uint4*)(q + 64 + j0) = o2.q;
    } else {
        int kt = s >> 6, key = s & 63, nt = key >> 4, l16k = key & 15;
        int qd = (j0 >> 3) & 3;
        int kk1 = j0 >> 5, kk2 = 2 + kk1;
        u16* tb = Kp + ((size_t)((b * NH_ + h) * 32 + kt)) * 8192;
        int lane = qd * 16 + l16k;
        *(uint4*)(tb + (kk1 * 4 + nt) * 512 + lane * 8) = o1.q;
        *(uint4*)(tb + (kk2 * 4 + nt) * 512 + lane * 8) = o2.q;
    }
}

// ---- V transpose -> fragment-packed Vp ----
__global__ __launch_bounds__(256) void transpose_v(const u16* __restrict__ V,
                                                   u16* __restrict__ Vp) {
    __shared__ u16 T[128][72];
    int stile = blockIdx.x, h = blockIdx.y, b = blockIdx.z;
    int tid = threadIdx.x;
    {
        int sl = tid >> 2, d0 = (tid & 3) * 32;
        const u16* vp = V + ((size_t)((b * SEQ_ + stile * 64 + sl) * NH_ + h)) * HD_ + d0;
        #pragma unroll
        for (int i = 0; i < 4; ++i) {
            union { uint4 q; u16 u[8]; } r;
            r.q = *(const uint4*)(vp + i * 8);
            #pragma unroll
            for (int j = 0; j < 8; ++j) T[d0 + i * 8 + j][sl] = r.u[j];
        }
    }
    __syncthreads();
    {
        int d = tid >> 1, kc = (tid & 1) * 32;
        int dt = d >> 4, l16v = d & 15, kk = kc >> 5;
        u16* tb = Vp + ((size_t)((b * NH_ + h) * 32 + stile)) * 8192 + (kk * 8 + dt) * 512;
        #pragma unroll
        for (int i = 0; i < 4; ++i)
            *(uint4*)(tb + (i * 16 + l16v) * 8) = *(const uint4*)&T[d][kc + i * 8];
    }
}

// ---- split-K flash attention, fixed-max softmax, DOUBLE-BUFFERED staging ----
// One barrier/iter: DMA for tile kt+1 issues right after the barrier that
// publishes tile kt, so each DMA has a full compute phase to land. Pt is
// per-wave (no barrier). 80 KB LDS -> 2 blocks/CU (deliberate trade).
__device__ const unsigned char QT_TAB[40] =
    {0,1,2,3,4,4,5,5,6,6,7,7,8,8,8,9,9,9,10,10,10,11,11,11,
     12,12,12,12,13,13,13,13,14,14,14,14,15,15,15,15};
__device__ const unsigned char CH_TAB[40] =
    {0,0,0,0,0,1,0,1,0,1,0,1,0,1,2,0,1,2,0,1,2,0,1,2,
     0,1,2,3,0,1,2,3,0,1,2,3,0,1,2,3};

__global__ __launch_bounds__(256, 2) void attn_k(const u16* __restrict__ Q,
                                                 const u16* __restrict__ Kp,
                                                 const u16* __restrict__ Vp,
                                                 u16* __restrict__ AO,
                                                 u16* __restrict__ PO,
                                                 float* __restrict__ Pl) {
    const int cid = blockIdx.x, h = blockIdx.y, b = blockIdx.z;
    const int qt = QT_TAB[cid], c = CH_TAB[cid];
    const int ntiles = 2 * qt + 2;
    const int nch = (ntiles + 7) >> 3;
    const int kt0 = c * 8;
    const int kt1 = (kt0 + 8 < ntiles) ? kt0 + 8 : ntiles;
    const int bh = b * NH_ + h;

    const int tid = threadIdx.x, wave = tid >> 6, lane = tid & 63;
    const int quad = lane >> 4, l16 = lane & 15;

    __shared__ alignas(16) u16 Ks[2][16 * 512];   // double-buffered K, 32 KB
    __shared__ alignas(16) u16 Vs[2][16 * 512];   // double-buffered V, 32 KB
    __shared__ alignas(16) u16 Pt[4][4][512];     // per-wave P^T B-frags, 16 KB

    bf16x8 qf[2][4];
    #pragma unroll
    for (int mt = 0; mt < 2; ++mt) {
        int sq = qt * 128 + wave * 32 + mt * 16 + l16;
        const u16* qp = Q + ((size_t)((b * SEQ_ + sq) * NH_ + h)) * HD_;
        #pragma unroll
        for (int kk = 0; kk < 4; ++kk)
            qf[mt][kk] = *(const bf16x8*)(qp + kk * 32 + quad * 8);
    }
    f32x4 oacc[2][8] = {};
    float l_run[2] = {0.f, 0.f};   // per-lane partial (this quad's keys only)
    const int q0 = qt * 128 + wave * 32 + l16;

    const u16* kpb = Kp + ((size_t)bh * 32) * 8192;
    const u16* vpb = Vp + ((size_t)bh * 32) * 8192;

    // prologue: DMA tile kt0 into buffer 0
    {
        const u16* kp_t = kpb + (size_t)kt0 * 8192;
        const u16* vp_t = vpb + (size_t)kt0 * 8192;
        #pragma unroll
        for (int i = 0; i < 4; ++i) {
            int f = wave * 4 + i;
            g2l16(kp_t + f * 512 + lane * 8, &Ks[0][f * 512]);
            g2l16(vp_t + f * 512 + lane * 8, &Vs[0][f * 512]);
        }
    }

    for (int kt = kt0; kt < kt1; ++kt) {
        const int buf = (kt - kt0) & 1;
        // drains this tile's DMA (issued one compute-phase ago) and proves all
        // waves finished reading the buffer we are about to overwrite
        __syncthreads();
        if (kt + 1 < kt1) {        // prefetch next tile into the other buffer
            const u16* kp_n = kpb + (size_t)(kt + 1) * 8192;
            const u16* vp_n = vpb + (size_t)(kt + 1) * 8192;
            #pragma unroll
            for (int i = 0; i < 4; ++i) {
                int f = wave * 4 + i;
                g2l16(kp_n + f * 512 + lane * 8, &Ks[buf ^ 1][f * 512]);
                g2l16(vp_n + f * 512 + lane * 8, &Vs[buf ^ 1][f * 512]);
            }
        }
        f32x4 sacc[2][4] = {};
        #pragma unroll
        for (int kk = 0; kk < 4; ++kk) {
            #pragma unroll
            for (int nt = 0; nt < 4; ++nt) {
                bf16x8 kf = *(const bf16x8*)&Ks[buf][(kk * 4 + nt) * 512 + lane * 8];
                sacc[0][nt] = mfma16(kf, qf[0][kk], sacc[0][nt]);
                sacc[1][nt] = mfma16(kf, qf[1][kk], sacc[1][nt]);
            }
        }
        const bool maskt = (kt >= 2 * qt);
        const int keyb = kt * 64 + quad * 4;
        #pragma unroll
        for (int mt = 0; mt < 2; ++mt) {
            const int qg = q0 + mt * 16;
            float ps = 0.f;
            #pragma unroll
            for (int nt = 0; nt < 4; ++nt) {
                float p[4];
                #pragma unroll
                for (int r = 0; r < 4; ++r) {
                    float x = sacc[mt][nt][r] - 32.0f;
                    if (maskt && (keyb + nt * 16 + r > qg)) x = -INFINITY;
                    p[r] = __builtin_amdgcn_exp2f(x);
                    ps += p[r];
                }
                ushort4 w4 = pack4(p[0], p[1], p[2], p[3]);
                int rowf = (((nt & 1) << 1) | (quad >> 1)) * 16 + l16;
                *(ushort4*)&Pt[wave][mt * 2 + (nt >> 1)][rowf * 8 + (quad & 1) * 4] = w4;
            }
            l_run[mt] += ps;
        }
        // O^T += V^T P^T (fixed max: no rescale; Pt per-wave, lgkmcnt only)
        #pragma unroll
        for (int kk = 0; kk < 2; ++kk) {
            bf16x8 pf0 = *(const bf16x8*)&Pt[wave][kk][(quad * 16 + l16) * 8];
            bf16x8 pf1 = *(const bf16x8*)&Pt[wave][2 + kk][(quad * 16 + l16) * 8];
            #pragma unroll
            for (int dt = 0; dt < 8; ++dt) {
                bf16x8 vf = *(const bf16x8*)&Vs[buf][(kk * 8 + dt) * 512 + lane * 8];
                oacc[0][dt] = mfma16(vf, pf0, oacc[0][dt]);
                oacc[1][dt] = mfma16(vf, pf1, oacc[1][dt]);
            }
        }
    }
    // final l reduction across quads (deferred from the K-loop)
    #pragma unroll
    for (int mt = 0; mt < 2; ++mt) {
        l_run[mt] += __shfl_xor(l_run[mt], 16, 64);
        l_run[mt] += __shfl_xor(l_run[mt], 32, 64);
    }
    if (nch == 1) {
        #pragma unroll
        for (int mt = 0; mt < 2; ++mt) {
            float invl = 1.0f / l_run[mt];
            int sq = q0 + mt * 16;
            u16* op = AO + ((size_t)((b * SEQ_ + sq) * NH_ + h)) * HD_ + quad * 4;
            #pragma unroll
            for (int dt = 0; dt < 8; ++dt) {
                ushort4 w4 = pack4(oacc[mt][dt][0] * invl, oacc[mt][dt][1] * invl,
                                   oacc[mt][dt][2] * invl, oacc[mt][dt][3] * invl);
                *(ushort4*)(op + dt * 16) = w4;
            }
        }
    } else {
        size_t pidx = ((size_t)bh * 16 + qt) * 4 + c;
        u16* po = PO + pidx * 16384;
        #pragma unroll
        for (int mt = 0; mt < 2; ++mt) {
            #pragma unroll
            for (int dt = 0; dt < 8; ++dt) {
                ushort4 w4 = pack4(oacc[mt][dt][0], oacc[mt][dt][1],
                                   oacc[mt][dt][2], oacc[mt][dt][3]);
                *(ushort4*)(po + ((wave * 16 + mt * 8 + dt) * 64 + lane) * 4) = w4;
            }
            if (quad == 0)
                Pl[pidx * 128 + wave * 32 + mt * 16 + l16] = l_run[mt];
        }
    }
}

// ---- combine partials for qt >= 4 (fixed max: plain sums) ----
__global__ __launch_bounds__(256) void combine_k(const u16* __restrict__ PO,
                                                 const float* __restrict__ Pl,
                                                 u16* __restrict__ AO) {
    const int qt = 4 + blockIdx.x, h = blockIdx.y, b = blockIdx.z;
    const int nch = (2 * qt + 2 + 7) >> 3;
    const int bh = b * NH_ + h;
    const int tid = threadIdx.x;
    const int q = tid >> 1, dh = tid & 1;
    const int wave = q >> 5, mt = (q >> 4) & 1, l16 = q & 15;
    size_t base = ((size_t)bh * 16 + qt) * 4;

    float L = 0.f;
    for (int c = 0; c < nch; ++c) L += Pl[(base + c) * 128 + q];
    float o[64];
    #pragma unroll
    for (int j = 0; j < 64; ++j) o[j] = 0.f;
    for (int c = 0; c < nch; ++c) {
        const u16* p = PO + (base + c) * 16384;
        #pragma unroll
        for (int dtl = 0; dtl < 4; ++dtl) {
            int dt = dh * 4 + dtl;
            #pragma unroll
            for (int quad = 0; quad < 4; ++quad) {
                union { ushort4 v; u16 u[4]; } t;
                t.v = *(const ushort4*)(p + ((wave * 16 + mt * 8 + dt) * 64
                                             + quad * 16 + l16) * 4);
                #pragma unroll
                for (int r = 0; r < 4; ++r)
                    o[dtl * 16 + quad * 4 + r] += bf2f(t.u[r]);
            }
        }
    }
    float invL = 1.0f / L;
    int sq = qt * 128 + q;
    u16* op = AO + ((size_t)((b * SEQ_ + sq) * NH_ + h)) * HD_ + dh * 64;
    union { uint4 v[8]; u16 u[64]; } t;
    #pragma unroll
    for (int j = 0; j < 64; ++j) t.u[j] = f2bf(o[j] * invL);
    #pragma unroll
    for (int i = 0; i < 8; ++i) *(uint4*)(op + i * 8) = t.v[i];
}

extern "C" void kernel_launch(void* const* d_in, const int* in_sizes, int n_in,
                              void* d_out, int out_size, void* d_ws, size_t ws_size,
                              hipStream_t stream) {
    const float* x  = (const float*)d_in[0];
    const float* Wq = (const float*)d_in[2];
    const float* bq = (const float*)d_in[3];
    const float* Wk = (const float*)d_in[4];
    const float* bk = (const float*)d_in[5];
    const float* Wv = (const float*)d_in[6];
    const float* bv = (const float*)d_in[7];
    const float* Wo = (const float*)d_in[8];
    const float* bo = (const float*)d_in[9];
    float* out = (float*)d_out;

    const size_t NE = (size_t)B_ * SEQ_ * NH_ * HD_;  // 5,242,880
    const size_t WN = (size_t)DIM_ * DIM_;            // 1,638,400
    u16* Qb  = (u16*)d_ws;         // raw Q -> later AO
    u16* Kb  = Qb + NE;            // raw K
    u16* Vb  = Kb + NE;            // raw V -> later Qr (roped Q)
    u16* Vp  = Vb + NE;            // fragment-packed V
    u16* xb  = Vp + NE;            // x bf16 -> later Kp (packed roped K)
    u16* Wqb = xb + NE;
    u16* Wkb = Wqb + WN;
    u16* Wvb = Wkb + WN;
    u16* Wob = Wvb + WN;
    float* ct = (float*)(Wob + WN);
    float* st = ct + (size_t)SEQ_ * 64;
    u16* PO  = (u16*)(st + (size_t)SEQ_ * 64);        // 1280 chunks x 16384 u16
    float* Pl = (float*)(PO + (size_t)B_ * NH_ * 16 * 4 * 16384);
    u16* Qr = Vb;   // roped Q (Vb dead after transpose_v)
    u16* Kp = xb;   // packed roped K (xb dead after qkv_gemm)
    u16* AO = Qb;   // attention output (Qb dead after rope_k)

    const int NCVT = (B_ * SEQ_ * DIM_ + 4 * (int)WN) / 8 / 256;  // 5760
    cvt_k<<<NCVT + 512, 256, 0, stream>>>(x, Wq, Wk, Wv, Wo,
                                          xb, Wqb, Wkb, Wvb, Wob, ct, st);

    qkv_gemm<<<dim3(30, 32), 256, 0, stream>>>(xb, Wqb, Wkb, Wvb, bq, bk, bv,
                                               Qb, Kb, Vb);

    transpose_v<<<dim3(SEQ_ / 64, NH_, B_), 256, 0, stream>>>(Vb, Vp);

    const float qsc = 0.08838834764831845f * 1.4426950408889634f;
    rope_k<<<(2 * B_ * SEQ_ * NH_ * 8) / 256, 256, 0, stream>>>(Qb, Kb, Qr, Kp,
                                                                ct, st, qsc);

    attn_k<<<dim3(40, NH_, B_), 256, 0, stream>>>(Qr, Kp, Vp, AO, PO, Pl);
    combine_k<<<dim3(12, NH_, B_), 256, 0, stream>>>(PO, Pl, AO);

    out_gemm<<<dim3(10, 32), 256, 0, stream>>>(AO, Wob, bo, out);
}

// Round 13
// 252.484 us; speedup vs baseline: 1.0218x; 1.0218x over previous
//
#include <hip/hip_runtime.h>
#include <cmath>

typedef unsigned short u16;
typedef __attribute__((ext_vector_type(8))) short bf16x8;
typedef __attribute__((ext_vector_type(4))) float f32x4;

#define B_    2
#define SEQ_  2048
#define NH_   10
#define HD_   128
#define DIM_  1280

__device__ __forceinline__ u16 f2bf(float f) {
    union { float f; unsigned u; } v; v.f = f;
    unsigned r = (v.u + 0x7fffu + ((v.u >> 16) & 1u)) >> 16;
    return (u16)r;
}
__device__ __forceinline__ float bf2f(u16 h) {
    union { unsigned u; float f; } v; v.u = ((unsigned)h) << 16;
    return v.f;
}
__device__ __forceinline__ f32x4 mfma16(bf16x8 a, bf16x8 b, f32x4 c) {
    return __builtin_amdgcn_mfma_f32_16x16x32_bf16(a, b, c, 0, 0, 0);
}
__device__ __forceinline__ void g2l16(const void* g, void* l) {
    __builtin_amdgcn_global_load_lds(
        (const __attribute__((address_space(1))) unsigned*)g,
        (__attribute__((address_space(3))) unsigned*)l, 16, 0, 0);
}
__device__ __forceinline__ ushort4 pack4(float a, float b, float c, float d) {
    ushort4 w; w.x = f2bf(a); w.y = f2bf(b); w.z = f2bf(c); w.w = f2bf(d);
    return w;
}

// ---- merged convert + sincos: x + 4 weights -> bf16, then ct/st tables ----
__global__ __launch_bounds__(256) void cvt_k(const float* __restrict__ x,
                                             const float* __restrict__ w0,
                                             const float* __restrict__ w1,
                                             const float* __restrict__ w2,
                                             const float* __restrict__ w3,
                                             u16* __restrict__ xb,
                                             u16* __restrict__ d0,
                                             u16* __restrict__ d1,
                                             u16* __restrict__ d2,
                                             u16* __restrict__ d3,
                                             float* __restrict__ ct,
                                             float* __restrict__ st) {
    const int NX = B_ * SEQ_ * DIM_;          // 5,242,880
    const int WN = DIM_ * DIM_;               // 1,638,400
    const int NCV = (NX + 4 * WN) / 8 / 256;  // 5760 convert blocks
    int bid = blockIdx.x;
    if (bid >= NCV) {                          // sincos tail: 512 blocks
        int idx = (bid - NCV) * 256 + threadIdx.x;
        int s = idx >> 6, j = idx & 63;
        float e = (float)j * (1.0f / 64.0f);
        float theta = 1.0f / powf(10000.0f, e);
        float ang = (float)s * theta;
        ct[idx] = cosf(ang);
        st[idx] = sinf(ang);
        return;
    }
    int i = (bid * 256 + threadIdx.x) * 8;
    const float* src; u16* dst; int off;
    if (i < NX) { src = x; dst = xb; off = i; }
    else {
        int j = i - NX; int w = j / WN; off = j - w * WN;
        src = (w == 0) ? w0 : (w == 1) ? w1 : (w == 2) ? w2 : w3;
        dst = (w == 0) ? d0 : (w == 1) ? d1 : (w == 2) ? d2 : d3;
    }
    float4 a0 = *(const float4*)(src + off);
    float4 a1 = *(const float4*)(src + off + 4);
    union { uint4 q; u16 u[8]; } t;
    t.u[0] = f2bf(a0.x); t.u[1] = f2bf(a0.y);
    t.u[2] = f2bf(a0.z); t.u[3] = f2bf(a0.w);
    t.u[4] = f2bf(a1.x); t.u[5] = f2bf(a1.y);
    t.u[6] = f2bf(a1.z); t.u[7] = f2bf(a1.w);
    *(uint4*)(dst + off) = t.q;
}

// ------- GEMM core: 128x128 tile, BK=64, global_load_lds DMA, XOR-swizzled
// 64-wide rows (conflict-free). Proven R11 structure. -------
template <typename OT>
__device__ __forceinline__ void gemm_core(const u16* __restrict__ A,
                                          const u16* __restrict__ W,
                                          const float* __restrict__ bias,
                                          OT* __restrict__ C,
                                          int m_blk, int n_blk,
                                          u16* As, u16* Bs) {
    const int tid = threadIdx.x;
    const int wave = tid >> 6, lane = tid & 63;
    const int quad = lane >> 4, l16 = lane & 15;
    const int w_m = (wave >> 1) * 64, w_n = (wave & 1) * 64;
    const int srow = wave * 32;
    const int lrow = lane >> 3;                       // 0..7
    const int csw = ((lane & 7) ^ lrow) * 8;          // swizzled src chunk
    const int rsw = l16 & 7;                          // reader chunk xor
    f32x4 acc[4][4] = {};

    const u16* pa = A + (size_t)(m_blk + srow + lrow) * DIM_ + csw;
    const u16* pb = W + (size_t)(n_blk + srow + lrow) * DIM_ + csw;

    for (int k0 = 0; k0 < DIM_; k0 += 64) {
        #pragma unroll
        for (int i = 0; i < 4; ++i) {
            g2l16(pa + k0 + i * 8 * DIM_, As + (srow + i * 8) * 64);
            g2l16(pb + k0 + i * 8 * DIM_, Bs + (srow + i * 8) * 64);
        }
        __syncthreads();          // staging visible
        #pragma unroll
        for (int kk = 0; kk < 2; ++kk) {
            bf16x8 af[4], bf[4];
            #pragma unroll
            for (int mt = 0; mt < 4; ++mt)
                af[mt] = *(const bf16x8*)&As[(w_m + mt * 16 + l16) * 64
                                             + ((kk * 4 + quad) ^ rsw) * 8];
            #pragma unroll
            for (int nt = 0; nt < 4; ++nt)
                bf[nt] = *(const bf16x8*)&Bs[(w_n + nt * 16 + l16) * 64
                                             + ((kk * 4 + quad) ^ rsw) * 8];
            #pragma unroll
            for (int mt = 0; mt < 4; ++mt)
                #pragma unroll
                for (int nt = 0; nt < 4; ++nt)
                    acc[mt][nt] = mfma16(af[mt], bf[nt], acc[mt][nt]);
        }
        __syncthreads();          // frag reads done before next staging
    }
    #pragma unroll
    for (int nt = 0; nt < 4; ++nt) {
        int col = n_blk + w_n + nt * 16 + l16;
        float bv = bias[col];
        #pragma unroll
        for (int mt = 0; mt < 4; ++mt) {
            #pragma unroll
            for (int r = 0; r < 4; ++r) {
                int row = m_blk + w_m + mt * 16 + quad * 4 + r;
                float v = acc[mt][nt][r] + bv;
                if constexpr (sizeof(OT) == 4) C[(size_t)row * DIM_ + col] = v;
                else C[(size_t)row * DIM_ + col] = (OT)f2bf(v);
            }
        }
    }
}

// flat grid 960; XCD-patch swizzle: xcd=id&7 -> (m-quarter, wn-half) patch,
// so each XCD's L2 holds 8 x-tiles (2.6MB) + 15 weight tiles (4.9MB).
__global__ __launch_bounds__(256) void qkv_gemm(const u16* __restrict__ xb,
                                                const u16* __restrict__ Wqb,
                                                const u16* __restrict__ Wkb,
                                                const u16* __restrict__ Wvb,
                                                const float* __restrict__ bq,
                                                const float* __restrict__ bk,
                                                const float* __restrict__ bv,
                                                u16* __restrict__ Qb,
                                                u16* __restrict__ Kb,
                                                u16* __restrict__ Vb) {
    __shared__ alignas(16) u16 As[128 * 64];
    __shared__ alignas(16) u16 Bs[128 * 64];
    int id = blockIdx.x;
    int xcd = id & 7, pid = id >> 3;          // pid 0..119
    int wn = (xcd & 1) * 15 + pid % 15;       // 0..29
    int m  = (xcd >> 1) * 8 + pid / 15;       // 0..31
    int wsel = wn / 10, n_blk = (wn % 10) * 128, m_blk = m * 128;
    const u16* W = (wsel == 0) ? Wqb : (wsel == 1) ? Wkb : Wvb;
    const float* bias = (wsel == 0) ? bq : (wsel == 1) ? bk : bv;
    u16* C = (wsel == 0) ? Qb : (wsel == 1) ? Kb : Vb;
    gemm_core<u16>(xb, W, bias, C, m_blk, n_blk, As, Bs);
}

// flat grid 320; per-XCD patch = 10 W-tiles + 4 AO-tiles (~4.6MB, L2-resident)
__global__ __launch_bounds__(256) void out_gemm(const u16* __restrict__ AO,
                                                const u16* __restrict__ Wob,
                                                const float* __restrict__ bo,
                                                float* __restrict__ C) {
    __shared__ alignas(16) u16 As[128 * 64];
    __shared__ alignas(16) u16 Bs[128 * 64];
    int id = blockIdx.x;
    int xcd = id & 7, pid = id >> 3;          // pid 0..39
    int n = pid % 10;                         // 0..9
    int m = xcd * 4 + pid / 10;               // 0..31
    gemm_core<float>(AO, Wob, bo, C, m * 128, n * 128, As, Bs);
}

// -------- RoPE: Q -> linear Qd (pre-scaled); K -> fragment-packed Kp --------
__global__ __launch_bounds__(256) void rope_k(const u16* __restrict__ Qs_,
                                              const u16* __restrict__ Ks_,
                                              u16* __restrict__ Qd,
                                              u16* __restrict__ Kp,
                                              const float* __restrict__ ct,
                                              const float* __restrict__ st,
                                              float qscale) {
    int t = blockIdx.x * 256 + threadIdx.x;     // 2*NR*8 threads total
    const int NR = B_ * SEQ_ * NH_;
    int rid = t >> 3, j0 = (t & 7) * 8;
    const bool isQ = (rid < NR);
    const u16* src = isQ ? Qs_ : Ks_;
    float sc = isQ ? qscale : 1.0f;
    if (!isQ) rid -= NR;
    int h = rid % NH_;
    int s = (rid / NH_) % SEQ_;
    int b = rid / (NH_ * SEQ_);
    const u16* p = src + (size_t)rid * HD_ + 2 * j0;
    union { uint4 q; u16 u[8]; } a0, a1, o1, o2;
    a0.q = *(const uint4*)p;
    a1.q = *(const uint4*)(p + 8);
    const float* cc = ct + (size_t)s * 64 + j0;
    const float* ss = st + (size_t)s * 64 + j0;
    #pragma unroll
    for (int j = 0; j < 8; ++j) {
        float x1 = bf2f((j < 4) ? a0.u[2 * j] : a1.u[2 * j - 8]);
        float x2 = bf2f((j < 4) ? a0.u[2 * j + 1] : a1.u[2 * j - 7]);
        float c = cc[j], sn = ss[j];
        o1.u[j] = f2bf((x1 * c - x2 * sn) * sc);
        o2.u[j] = f2bf((x1 * sn + x2 * c) * sc);
    }
    if (isQ) {
        u16* q = Qd + (size_t)(((size_t)b * SEQ_ + s) * NH_ + h) * HD_;
        *(uint4*)(q + j0) = o1.q;
        *(uint4*)(q + 64 + j0) = o2.q;
    } else {
        int kt = s >> 6, key = s & 63, nt = key >> 4, l16k = key & 15;
        int qd = (j0 >> 3) & 3;
        int kk1 = j0 >> 5, kk2 = 2 + kk1;
        u16* tb = Kp + ((size_t)((b * NH_ + h) * 32 + kt)) * 8192;
        int lane = qd * 16 + l16k;
        *(uint4*)(tb + (kk1 * 4 + nt) * 512 + lane * 8) = o1.q;
        *(uint4*)(tb + (kk2 * 4 + nt) * 512 + lane * 8) = o2.q;
    }
}

// ---- V transpose -> fragment-packed Vp ----
__global__ __launch_bounds__(256) void transpose_v(const u16* __restrict__ V,
                                                   u16* __restrict__ Vp) {
    __shared__ u16 T[128][72];
    int stile = blockIdx.x, h = blockIdx.y, b = blockIdx.z;
    int tid = threadIdx.x;
    {
        int sl = tid >> 2, d0 = (tid & 3) * 32;
        const u16* vp = V + ((size_t)((b * SEQ_ + stile * 64 + sl) * NH_ + h)) * HD_ + d0;
        #pragma unroll
        for (int i = 0; i < 4; ++i) {
            union { uint4 q; u16 u[8]; } r;
            r.q = *(const uint4*)(vp + i * 8);
            #pragma unroll
            for (int j = 0; j < 8; ++j) T[d0 + i * 8 + j][sl] = r.u[j];
        }
    }
    __syncthreads();
    {
        int d = tid >> 1, kc = (tid & 1) * 32;
        int dt = d >> 4, l16v = d & 15, kk = kc >> 5;
        u16* tb = Vp + ((size_t)((b * NH_ + h) * 32 + stile)) * 8192 + (kk * 8 + dt) * 512;
        #pragma unroll
        for (int i = 0; i < 4; ++i)
            *(uint4*)(tb + (i * 16 + l16v) * 8) = *(const uint4*)&T[d][kc + i * 8];
    }
}

// ---- split-K flash attention, fixed-max softmax (R11-proven version) ----
__device__ const unsigned char QT_TAB[40] =
    {0,1,2,3,4,4,5,5,6,6,7,7,8,8,8,9,9,9,10,10,10,11,11,11,
     12,12,12,12,13,13,13,13,14,14,14,14,15,15,15,15};
__device__ const unsigned char CH_TAB[40] =
    {0,0,0,0,0,1,0,1,0,1,0,1,0,1,2,0,1,2,0,1,2,0,1,2,
     0,1,2,3,0,1,2,3,0,1,2,3,0,1,2,3};

__global__ __launch_bounds__(256, 3) void attn_k(const u16* __restrict__ Q,
                                                 const u16* __restrict__ Kp,
                                                 const u16* __restrict__ Vp,
                                                 u16* __restrict__ AO,
                                                 u16* __restrict__ PO,
                                                 float* __restrict__ Pl) {
    const int cid = blockIdx.x, h = blockIdx.y, b = blockIdx.z;
    const int qt = QT_TAB[cid], c = CH_TAB[cid];
    const int ntiles = 2 * qt + 2;
    const int nch = (ntiles + 7) >> 3;
    const int kt0 = c * 8;
    const int kt1 = (kt0 + 8 < ntiles) ? kt0 + 8 : ntiles;
    const int bh = b * NH_ + h;

    const int tid = threadIdx.x, wave = tid >> 6, lane = tid & 63;
    const int quad = lane >> 4, l16 = lane & 15;

    __shared__ alignas(16) u16 Ks[16 * 512];     // packed K tile, 16 KB
    __shared__ alignas(16) u16 Vs[16 * 512];     // packed V tile, 16 KB
    __shared__ alignas(16) u16 Pt[4][4][512];    // per-wave P^T B-frags, 16 KB

    bf16x8 qf[2][4];
    #pragma unroll
    for (int mt = 0; mt < 2; ++mt) {
        int sq = qt * 128 + wave * 32 + mt * 16 + l16;
        const u16* qp = Q + ((size_t)((b * SEQ_ + sq) * NH_ + h)) * HD_;
        #pragma unroll
        for (int kk = 0; kk < 4; ++kk)
            qf[mt][kk] = *(const bf16x8*)(qp + kk * 32 + quad * 8);
    }
    f32x4 oacc[2][8] = {};
    float l_run[2] = {0.f, 0.f};   // per-lane partial (this quad's keys only)
    const int q0 = qt * 128 + wave * 32 + l16;

    const u16* kpb = Kp + ((size_t)bh * 32) * 8192;
    const u16* vpb = Vp + ((size_t)bh * 32) * 8192;

    for (int kt = kt0; kt < kt1; ++kt) {
        const u16* kp_t = kpb + (size_t)kt * 8192;
        const u16* vp_t = vpb + (size_t)kt * 8192;
        #pragma unroll
        for (int i = 0; i < 4; ++i) {
            int f = wave * 4 + i;
            g2l16(kp_t + f * 512 + lane * 8, &Ks[f * 512]);
            g2l16(vp_t + f * 512 + lane * 8, &Vs[f * 512]);
        }
        __syncthreads();
        f32x4 sacc[2][4] = {};
        #pragma unroll
        for (int kk = 0; kk < 4; ++kk) {
            #pragma unroll
            for (int nt = 0; nt < 4; ++nt) {
                bf16x8 kf = *(const bf16x8*)&Ks[(kk * 4 + nt) * 512 + lane * 8];
                sacc[0][nt] = mfma16(kf, qf[0][kk], sacc[0][nt]);
                sacc[1][nt] = mfma16(kf, qf[1][kk], sacc[1][nt]);
            }
        }
        const bool maskt = (kt >= 2 * qt);
        const int keyb = kt * 64 + quad * 4;
        #pragma unroll
        for (int mt = 0; mt < 2; ++mt) {
            const int qg = q0 + mt * 16;
            float ps = 0.f;
            #pragma unroll
            for (int nt = 0; nt < 4; ++nt) {
                float p[4];
                #pragma unroll
                for (int r = 0; r < 4; ++r) {
                    float x = sacc[mt][nt][r] - 32.0f;
                    if (maskt && (keyb + nt * 16 + r > qg)) x = -INFINITY;
                    p[r] = __builtin_amdgcn_exp2f(x);
                    ps += p[r];
                }
                ushort4 w4 = pack4(p[0], p[1], p[2], p[3]);
                int rowf = (((nt & 1) << 1) | (quad >> 1)) * 16 + l16;
                *(ushort4*)&Pt[wave][mt * 2 + (nt >> 1)][rowf * 8 + (quad & 1) * 4] = w4;
            }
            l_run[mt] += ps;
        }
        // O^T += V^T P^T (no rescale needed: fixed max)
        #pragma unroll
        for (int kk = 0; kk < 2; ++kk) {
            bf16x8 pf0 = *(const bf16x8*)&Pt[wave][kk][(quad * 16 + l16) * 8];
            bf16x8 pf1 = *(const bf16x8*)&Pt[wave][2 + kk][(quad * 16 + l16) * 8];
            #pragma unroll
            for (int dt = 0; dt < 8; ++dt) {
                bf16x8 vf = *(const bf16x8*)&Vs[(kk * 8 + dt) * 512 + lane * 8];
                oacc[0][dt] = mfma16(vf, pf0, oacc[0][dt]);
                oacc[1][dt] = mfma16(vf, pf1, oacc[1][dt]);
            }
        }
        __syncthreads();
    }
    // final l reduction across quads (deferred from the K-loop)
    #pragma unroll
    for (int mt = 0; mt < 2; ++mt) {
        l_run[mt] += __shfl_xor(l_run[mt], 16, 64);
        l_run[mt] += __shfl_xor(l_run[mt], 32, 64);
    }
    if (nch == 1) {
        #pragma unroll
        for (int mt = 0; mt < 2; ++mt) {
            float invl = 1.0f / l_run[mt];
            int sq = q0 + mt * 16;
            u16* op = AO + ((size_t)((b * SEQ_ + sq) * NH_ + h)) * HD_ + quad * 4;
            #pragma unroll
            for (int dt = 0; dt < 8; ++dt) {
                ushort4 w4 = pack4(oacc[mt][dt][0] * invl, oacc[mt][dt][1] * invl,
                                   oacc[mt][dt][2] * invl, oacc[mt][dt][3] * invl);
                *(ushort4*)(op + dt * 16) = w4;
            }
        }
    } else {
        size_t pidx = ((size_t)bh * 16 + qt) * 4 + c;
        u16* po = PO + pidx * 16384;
        #pragma unroll
        for (int mt = 0; mt < 2; ++mt) {
            #pragma unroll
            for (int dt = 0; dt < 8; ++dt) {
                ushort4 w4 = pack4(oacc[mt][dt][0], oacc[mt][dt][1],
                                   oacc[mt][dt][2], oacc[mt][dt][3]);
                *(ushort4*)(po + ((wave * 16 + mt * 8 + dt) * 64 + lane) * 4) = w4;
            }
            if (quad == 0)
                Pl[pidx * 128 + wave * 32 + mt * 16 + l16] = l_run[mt];
        }
    }
}

// ---- combine partials for qt >= 4 (fixed max: plain sums) ----
__global__ __launch_bounds__(256) void combine_k(const u16* __restrict__ PO,
                                                 const float* __restrict__ Pl,
                                                 u16* __restrict__ AO) {
    const int qt = 4 + blockIdx.x, h = blockIdx.y, b = blockIdx.z;
    const int nch = (2 * qt + 2 + 7) >> 3;
    const int bh = b * NH_ + h;
    const int tid = threadIdx.x;
    const int q = tid >> 1, dh = tid & 1;
    const int wave = q >> 5, mt = (q >> 4) & 1, l16 = q & 15;
    size_t base = ((size_t)bh * 16 + qt) * 4;

    float L = 0.f;
    for (int c = 0; c < nch; ++c) L += Pl[(base + c) * 128 + q];
    float o[64];
    #pragma unroll
    for (int j = 0; j < 64; ++j) o[j] = 0.f;
    for (int c = 0; c < nch; ++c) {
        const u16* p = PO + (base + c) * 16384;
        #pragma unroll
        for (int dtl = 0; dtl < 4; ++dtl) {
            int dt = dh * 4 + dtl;
            #pragma unroll
            for (int quad = 0; quad < 4; ++quad) {
                union { ushort4 v; u16 u[4]; } t;
                t.v = *(const ushort4*)(p + ((wave * 16 + mt * 8 + dt) * 64
                                             + quad * 16 + l16) * 4);
                #pragma unroll
                for (int r = 0; r < 4; ++r)
                    o[dtl * 16 + quad * 4 + r] += bf2f(t.u[r]);
            }
        }
    }
    float invL = 1.0f / L;
    int sq = qt * 128 + q;
    u16* op = AO + ((size_t)((b * SEQ_ + sq) * NH_ + h)) * HD_ + dh * 64;
    union { uint4 v[8]; u16 u[64]; } t;
    #pragma unroll
    for (int j = 0; j < 64; ++j) t.u[j] = f2bf(o[j] * invL);
    #pragma unroll
    for (int i = 0; i < 8; ++i) *(uint4*)(op + i * 8) = t.v[i];
}

extern "C" void kernel_launch(void* const* d_in, const int* in_sizes, int n_in,
                              void* d_out, int out_size, void* d_ws, size_t ws_size,
                              hipStream_t stream) {
    const float* x  = (const float*)d_in[0];
    const float* Wq = (const float*)d_in[2];
    const float* bq = (const float*)d_in[3];
    const float* Wk = (const float*)d_in[4];
    const float* bk = (const float*)d_in[5];
    const float* Wv = (const float*)d_in[6];
    const float* bv = (const float*)d_in[7];
    const float* Wo = (const float*)d_in[8];
    const float* bo = (const float*)d_in[9];
    float* out = (float*)d_out;

    const size_t NE = (size_t)B_ * SEQ_ * NH_ * HD_;  // 5,242,880
    const size_t WN = (size_t)DIM_ * DIM_;            // 1,638,400
    u16* Qb  = (u16*)d_ws;         // raw Q -> later AO
    u16* Kb  = Qb + NE;            // raw K
    u16* Vb  = Kb + NE;            // raw V -> later Qr (roped Q)
    u16* Vp  = Vb + NE;            // fragment-packed V
    u16* xb  = Vp + NE;            // x bf16 -> later Kp (packed roped K)
    u16* Wqb = xb + NE;
    u16* Wkb = Wqb + WN;
    u16* Wvb = Wkb + WN;
    u16* Wob = Wvb + WN;
    float* ct = (float*)(Wob + WN);
    float* st = ct + (size_t)SEQ_ * 64;
    u16* PO  = (u16*)(st + (size_t)SEQ_ * 64);        // 1280 chunks x 16384 u16
    float* Pl = (float*)(PO + (size_t)B_ * NH_ * 16 * 4 * 16384);
    u16* Qr = Vb;   // roped Q (Vb dead after transpose_v)
    u16* Kp = xb;   // packed roped K (xb dead after qkv_gemm)
    u16* AO = Qb;   // attention output (Qb dead after rope_k)

    const int NCVT = (B_ * SEQ_ * DIM_ + 4 * (int)WN) / 8 / 256;  // 5760
    cvt_k<<<NCVT + 512, 256, 0, stream>>>(x, Wq, Wk, Wv, Wo,
                                          xb, Wqb, Wkb, Wvb, Wob, ct, st);

    qkv_gemm<<<dim3(960), 256, 0, stream>>>(xb, Wqb, Wkb, Wvb, bq, bk, bv,
                                            Qb, Kb, Vb);

    transpose_v<<<dim3(SEQ_ / 64, NH_, B_), 256, 0, stream>>>(Vb, Vp);

    const float qsc = 0.08838834764831845f * 1.4426950408889634f;
    rope_k<<<(2 * B_ * SEQ_ * NH_ * 8) / 256, 256, 0, stream>>>(Qb, Kb, Qr, Kp,
                                                                ct, st, qsc);

    attn_k<<<dim3(40, NH_, B_), 256, 0, stream>>>(Qr, Kp, Vp, AO, PO, Pl);
    combine_k<<<dim3(12, NH_, B_), 256, 0, stream>>>(PO, Pl, AO);

    out_gemm<<<dim3(320), 256, 0, stream>>>(AO, Wob, bo, out);
}